// Round 19
// baseline (1446.169 us; speedup 1.0000x reference)
//
#include <hip/hip_runtime.h>
#include <cstdint>
#include <cstddef>

#define NB 256   // batch
#define NT 512   // time steps
#define ND 64    // input dim
#define NH 512   // hidden dim

// ---- tagged-granule fallback (R16) constants ----
#define GRW   171
#define STRW  172
#define STRCB 688
#define STRBG 2752
#define STRBUF 44032
#define NGTOT 88064

typedef __attribute__((ext_vector_type(8))) _Float16 half8;
typedef __attribute__((ext_vector_type(4))) float f32x4;
typedef unsigned long long ull;

__device__ __forceinline__ float tanh_fast(float x) {
  float ax = fabsf(x);
  float e  = __expf(-2.0f * ax);
  float t  = (1.0f - e) * __frcp_rn(1.0f + e);
  return copysignf(t, x);
}
__device__ __forceinline__ float tanh_cheap(float x) {
  float z = fminf(fmaxf(x, -15.f), 15.f);
  float e = __expf(2.f * z);
  float d = e + 1.f;
  float r;
  asm("v_rcp_f32 %0, %1" : "=v"(r) : "v"(d));
  return (e - 1.f) * r;
}
__device__ __forceinline__ unsigned short f16b(float v) {
  _Float16 h = (_Float16)v;
  union { _Float16 h; unsigned short u; } c; c.h = h;
  return c.u;
}

// Pack W (W_hh | W_ih) fp16 fragment-major (R10/R16 layout, proven).
__global__ void prep_kernel(const float* __restrict__ whh,
                            const float* __restrict__ wih,
                            _Float16* __restrict__ wpk) {
  const int id = blockIdx.x * 256 + threadIdx.x;   // 0..36863
  if (id >= 18 * 4 * 8 * 64) return;
  const int lane = id & 63;
  const int j    = (id >> 6) & 7;
  const int cbv  = (id >> 9) & 3;
  const int kt   = id >> 11;
  const int n    = cbv * 128 + j * 16 + (lane & 15);
  const int kb   = kt * 32 + (lane >> 4) * 8;
  half8 o;
#pragma unroll
  for (int e = 0; e < 8; ++e) {
    const int k = kb + e;
    const float v = (kt < 16) ? whh[(size_t)n * NH + k]
                              : wih[(size_t)n * ND + (k - NH)];
    o[e] = (_Float16)v;
  }
  *(half8*)(wpk + (size_t)id * 8) = o;
}

// ======================= MAIN PATH (zero-exchange) =======================
// R19: SWAPPED MFMA OPERANDS (A=W-frag, B=h-frag; frag layouts identical on
// gfx950) -> D'[col][batch]: lane holds 4 CONTIGUOUS h-cols per nt for batch
// row (lane&15). h-writes: 16x ds_write_b16 -> 4x ds_write_b64; out-reduce:
// 16 bpermutes -> 1 scalar + 2 shfl_xor. LDS ops/CU-step 512 -> ~304.

// xp precompute, swapped layout: xpf[bg][t][w][lane][16] where value j
// (nt=j>>2 within o0/o1 pairs) = xp[batch lane&15][col w*64+nt*16+lg*4+r]+bias.
__global__ __launch_bounds__(512) void xp_kernel(
    const float* __restrict__ x, const _Float16* __restrict__ wpk,
    const float* __restrict__ bih, const float* __restrict__ bhh,
    _Float16* __restrict__ xpf)
{
  const int bg   = blockIdx.x >> 5;
  const int tc   = blockIdx.x & 31;
  const int w    = threadIdx.x >> 6;
  const int lane = threadIdx.x & 63;
  const int lm   = lane & 15;
  const int lg   = lane >> 4;
  const int lkb  = lg * 8;
  const int bm   = bg * 16;

  half8 wx[2][4];
#pragma unroll
  for (int q = 0; q < 2; ++q)
#pragma unroll
    for (int nt = 0; nt < 4; ++nt) {
      const int u = (16 + q) * 32 + w * 4 + nt;
      wx[q][nt] = *(const half8*)(wpk + (size_t)u * 512 + lane * 8);
    }
  // per-lane bias vector: bv4[nt][r] = bias(col = w*64 + nt*16 + lg*4 + r)
  f32x4 bv4[4];
#pragma unroll
  for (int nt = 0; nt < 4; ++nt)
#pragma unroll
    for (int r = 0; r < 4; ++r) {
      const int n = w * 64 + nt * 16 + lg * 4 + r;
      bv4[nt][r] = bih[n] + bhh[n];
    }

  for (int tt = 0; tt < 16; ++tt) {
    const int t = tc * 16 + tt;
    const float* xp_ = x + ((size_t)(bm + lm) * NT + t) * ND + lkb;
    half8 ax[2];
#pragma unroll
    for (int q = 0; q < 2; ++q) {
      float v[8];
      *(f32x4*)&v[0] = *(const f32x4*)(xp_ + q * 32);
      *(f32x4*)&v[4] = *(const f32x4*)(xp_ + q * 32 + 4);
#pragma unroll
      for (int e = 0; e < 8; ++e) ax[q][e] = (_Float16)v[e];
    }
    f32x4 acc[4];
#pragma unroll
    for (int nt = 0; nt < 4; ++nt) acc[nt] = bv4[nt];
#pragma unroll
    for (int q = 0; q < 2; ++q) {   // SWAPPED: A = W-frag, B = x-frag
      acc[0] = __builtin_amdgcn_mfma_f32_16x16x32_f16(wx[q][0], ax[q], acc[0], 0, 0, 0);
      acc[1] = __builtin_amdgcn_mfma_f32_16x16x32_f16(wx[q][1], ax[q], acc[1], 0, 0, 0);
      acc[2] = __builtin_amdgcn_mfma_f32_16x16x32_f16(wx[q][2], ax[q], acc[2], 0, 0, 0);
      acc[3] = __builtin_amdgcn_mfma_f32_16x16x32_f16(wx[q][3], ax[q], acc[3], 0, 0, 0);
    }
    half8 o0, o1;
#pragma unroll
    for (int j = 0; j < 8; ++j) {
      o0[j] = (_Float16)acc[j >> 2][j & 3];
      o1[j] = (_Float16)acc[2 + (j >> 2)][j & 3];
    }
    _Float16* dst = xpf + ((((size_t)bg * NT + t) * 8 + w) * 64 + lane) * 16;
    *(half8*)dst = o0;
    *(half8*)(dst + 8) = o1;
  }
}

// Zero-exchange recurrence, swapped-operand layout.
__global__ __launch_bounds__(512, 2) void rnn_local(
    const _Float16* __restrict__ wpk, const _Float16* __restrict__ xpf,
    const float* __restrict__ who, float* __restrict__ partial)
{
  __shared__ __align__(16) _Float16 wlds[4][8][4][64][8];  // 128 KiB
  __shared__ __align__(16) _Float16 hst[16][520];          // 16.6 KiB
  // no posum: per-wave global partials

  const int tid  = threadIdx.x;
  const int bg   = blockIdx.x;
  const int w    = tid >> 6;
  const int lane = tid & 63;
  const int lm   = lane & 15;
  const int lg   = lane >> 4;
  const int lkb  = lg * 8;
  const int bm   = bg * 16;

  // ---- W_hh kt 0..11 -> VGPRs (static indices only) ----
  half8 wv[12][4];
#pragma unroll
  for (int kt = 0; kt < 12; ++kt)
#pragma unroll
    for (int nt = 0; nt < 4; ++nt) {
      const int u = kt * 32 + w * 4 + nt;
      wv[kt][nt] = *(const half8*)(wpk + (size_t)u * 512 + lane * 8);
    }
  // ---- W_hh kt 12..15 -> LDS ----
  for (int i = tid; i < 8192; i += 512) {
    const int ln  = i & 63;
    const int nt  = (i >> 6) & 3;
    const int ww  = (i >> 8) & 7;
    const int ktl = i >> 11;
    const int u   = (12 + ktl) * 32 + ww * 4 + nt;
    *(half8*)&wlds[ktl][ww][nt][ln][0] =
        *(const half8*)(wpk + (size_t)u * 512 + ln * 8);
  }
  // out-weights for this lane's 16 (nt,r) cols, packed fp16 (8 regs)
  half8 wovh[2];
#pragma unroll
  for (int j = 0; j < 8; ++j) {
    wovh[0][j] = (_Float16)who[w * 64 + (j >> 2) * 16 + lg * 4 + (j & 3)];
    wovh[1][j] = (_Float16)who[w * 64 + (2 + (j >> 2)) * 16 + lg * 4 + (j & 3)];
  }

  // h(-1) = 0
  for (int i = tid; i < 16 * 520 / 2; i += 512)
    ((unsigned*)&hst[0][0])[i] = 0u;
  __syncthreads();

  // xp(0) prefetch
  const _Float16* xpb = xpf + (((size_t)bg * NT * 8 + w) * 64 + lane) * 16;
  half8 xq0 = *(const half8*)xpb;
  half8 xq1 = *(const half8*)(xpb + 8);

  float* pbase = partial + ((size_t)w * NB + bm) * NT;

  for (int t = 0; t < NT; ++t) {
    // ---- acc init from xp fragments (bias folded in) ----
    f32x4 acc[4];
    acc[0] = (f32x4){(float)xq0[0], (float)xq0[1], (float)xq0[2], (float)xq0[3]};
    acc[1] = (f32x4){(float)xq0[4], (float)xq0[5], (float)xq0[6], (float)xq0[7]};
    acc[2] = (f32x4){(float)xq1[0], (float)xq1[1], (float)xq1[2], (float)xq1[3]};
    acc[3] = (f32x4){(float)xq1[4], (float)xq1[5], (float)xq1[6], (float)xq1[7]};

    // xp(t+1) prefetch: latency hides under MFMA phase
    if (t + 1 < NT) {
      const _Float16* nx = xpb + (size_t)(t + 1) * 8192;
      xq0 = *(const half8*)nx;
      xq1 = *(const half8*)(nx + 8);
    }

    // ---- 16 K-tiles, SWAPPED operands: A = W-frag, B = h-frag ----
#pragma unroll
    for (int kt = 0; kt < 12; ++kt) {
      half8 ah = *(const half8*)&hst[lm][kt * 32 + lkb];
      acc[0] = __builtin_amdgcn_mfma_f32_16x16x32_f16(wv[kt][0], ah, acc[0], 0, 0, 0);
      acc[1] = __builtin_amdgcn_mfma_f32_16x16x32_f16(wv[kt][1], ah, acc[1], 0, 0, 0);
      acc[2] = __builtin_amdgcn_mfma_f32_16x16x32_f16(wv[kt][2], ah, acc[2], 0, 0, 0);
      acc[3] = __builtin_amdgcn_mfma_f32_16x16x32_f16(wv[kt][3], ah, acc[3], 0, 0, 0);
    }
#pragma unroll
    for (int ktl = 0; ktl < 4; ++ktl) {
      half8 ah = *(const half8*)&hst[lm][(12 + ktl) * 32 + lkb];
      half8 b0 = *(const half8*)&wlds[ktl][w][0][lane][0];
      half8 b1 = *(const half8*)&wlds[ktl][w][1][lane][0];
      half8 b2 = *(const half8*)&wlds[ktl][w][2][lane][0];
      half8 b3 = *(const half8*)&wlds[ktl][w][3][lane][0];
      acc[0] = __builtin_amdgcn_mfma_f32_16x16x32_f16(b0, ah, acc[0], 0, 0, 0);
      acc[1] = __builtin_amdgcn_mfma_f32_16x16x32_f16(b1, ah, acc[1], 0, 0, 0);
      acc[2] = __builtin_amdgcn_mfma_f32_16x16x32_f16(b2, ah, acc[2], 0, 0, 0);
      acc[3] = __builtin_amdgcn_mfma_f32_16x16x32_f16(b3, ah, acc[3], 0, 0, 0);
    }

    __syncthreads();   // A: all hst reads complete

    // ---- epilogue: tanh -> hst (4x b64, contiguous) + out partial ----
    float po = 0.f;
#pragma unroll
    for (int nt = 0; nt < 4; ++nt) {
      ull pk = 0;
#pragma unroll
      for (int r = 0; r < 4; ++r) {
        float hv = tanh_cheap(acc[nt][r]);
        pk |= (ull)f16b(hv) << (16 * r);
        const int j = nt * 4 + r;
        po += hv * (float)wovh[j >> 3][j & 7];
      }
      *(ull*)&hst[lm][w * 64 + nt * 16 + lg * 4] = pk;   // ds_write_b64
    }
    po += __shfl_xor(po, 16, 64);
    po += __shfl_xor(po, 32, 64);

    __syncthreads();   // B: h(t) visible to all waves

    if (lane < 16) pbase[(size_t)lane * NT + t] = po;   // drains next barrier A
  }
}

// out[b][t] = b_ho + sum_w partial[w][b][t]
__global__ void combine8_kernel(const float* __restrict__ partial,
                                const float* __restrict__ bho,
                                float* __restrict__ out) {
  int id = blockIdx.x * 256 + threadIdx.x;   // 131072
  float s = bho[0];
#pragma unroll
  for (int w = 0; w < 8; ++w) s += partial[(size_t)w * NB * NT + id];
  out[id] = s;
}

// ======================= FALLBACK PATH (R16, proven) =======================

__global__ void init_kernel(ull* __restrict__ hg) {
  int i = blockIdx.x * 256 + threadIdx.x;
  if (i < NGTOT) hg[i] = 0ull;
}
__global__ void combine_kernel(const float* __restrict__ partial,
                               const float* __restrict__ bho,
                               float* __restrict__ out) {
  int id = blockIdx.x * 256 + threadIdx.x;
  out[id] = bho[0] + partial[id] + partial[id + NB * NT]
          + partial[id + 2 * NB * NT] + partial[id + 3 * NB * NT];
}

__global__ __launch_bounds__(256) void rnn_tag(
    const float* __restrict__ x, const _Float16* __restrict__ wpk,
    const float* __restrict__ bih, const float* __restrict__ bhh,
    const float* __restrict__ who,
    ull* __restrict__ hglob, float* __restrict__ partial)
{
  __shared__ unsigned short hpeer[16][522];
  __shared__ unsigned short tstage[4][520];
  __shared__ float posum[2][4][16];

  const int tid  = threadIdx.x;
  const int bid  = blockIdx.x;
  const int bg   = bid >> 2;
  const int cb   = bid & 3;
  const int w    = tid >> 6;
  const int lane = tid & 63;
  const int lm   = lane & 15;
  const int lg   = lane >> 4;
  const int lkb  = lg * 8;
  const int bm   = bg * 16;
  const int n0   = cb * 128 + w * 32;

  half8 wv[18][2];
#pragma unroll
  for (int kt = 0; kt < 18; ++kt)
#pragma unroll
    for (int nt = 0; nt < 2; ++nt)
      wv[kt][nt] = *(const half8*)(wpk +
        (size_t)(((kt * 4 + cb) * 8 + (w * 2 + nt)) * 64 + lane) * 8);

  float bv[2], wov[2];
#pragma unroll
  for (int nt = 0; nt < 2; ++nt) {
    const int n = n0 + nt * 16 + lm;
    bv[nt]  = bih[n] + bhh[n];
    wov[nt] = who[n];
  }
  for (int i = tid; i < 16 * 522 / 2; i += 256)
    ((unsigned*)&hpeer[0][0])[i] = 0u;
  __syncthreads();

  const float* xrow = x + (size_t)(bm + lm) * NT * ND + lkb;
  f32x4 xr[4];
#pragma unroll
  for (int xt = 0; xt < 2; ++xt) {
    xr[2 * xt]     = *(const f32x4*)(xrow + xt * 32);
    xr[2 * xt + 1] = *(const f32x4*)(xrow + xt * 32 + 4);
  }

  unsigned foff[9]; int bcol[9], gv[9];
  unsigned fvalid = 0;
#pragma unroll
  for (int k = 0; k < 9; ++k) {
    const int idx = tid + k * 256;
    if (idx < 2052) {
      const int pi  = idx / 684;
      const int rem = idx - pi * 684;
      const int wp  = rem / GRW;
      const int g   = rem - wp * GRW;
      const int scb = pi + (pi >= cb);
      foff[k] = (unsigned)(bg * STRBG + scb * STRCB + wp * STRW + g);
      bcol[k] = scb * 128 + wp * 32;
      gv[k]   = g;
      fvalid |= 1u << k;
    } else { foff[k] = 0; bcol[k] = 0; gv[k] = 0; }
  }
  const unsigned mypub = (unsigned)(bg * STRBG + cb * STRCB + w * STRW);

  ull fq[9];
  half8 ax[2];
  f32x4 acc[2];

  for (int t = 0; t < NT; ++t) {
    if (t > 0) {
      const unsigned short tagT = (unsigned short)t;
      const size_t bufb = (size_t)((t + 1) & 1) * STRBUF;
      int iter = 0;
      for (;;) {
        asm volatile("s_waitcnt vmcnt(0)" ::: "memory");
        unsigned pend = 0;
#pragma unroll
        for (int k = 0; k < 9; ++k)
          if ((fvalid >> k & 1u) && (unsigned short)(fq[k] >> 48) != tagT)
            pend |= 1u << k;
        if (__all(pend == 0u)) break;
        if (++iter > (1 << 22)) break;
        __builtin_amdgcn_s_sleep(1);
#pragma unroll
        for (int k = 0; k < 9; ++k)
          if (pend >> k & 1u)
            fq[k] = __hip_atomic_load(hglob + bufb + foff[k],
                                      __ATOMIC_RELAXED, __HIP_MEMORY_SCOPE_AGENT);
      }
#pragma unroll
      for (int k = 0; k < 9; ++k) {
        if (!(fvalid >> k & 1u)) continue;
        const ull v = fq[k];
        const int g3 = 3 * gv[k];
#pragma unroll
        for (int j = 0; j < 3; ++j) {
          const int p = g3 + j;
          if (p < 512)
            hpeer[p & 15][bcol[k] + (p >> 4)] = (unsigned short)(v >> (16 * j));
        }
      }
      __syncthreads();
      if (w == 0 && lane < 16) {
        float s4 = posum[(t - 1) & 1][0][lane] + posum[(t - 1) & 1][1][lane]
                 + posum[(t - 1) & 1][2][lane] + posum[(t - 1) & 1][3][lane];
        partial[((size_t)cb * NB + bm + lane) * NT + (t - 1)] = s4;
      }
    }

#pragma unroll
    for (int xt = 0; xt < 2; ++xt) {
      float v[8];
      *(f32x4*)&v[0] = xr[2 * xt];
      *(f32x4*)&v[4] = xr[2 * xt + 1];
#pragma unroll
      for (int e = 0; e < 8; ++e) ax[xt][e] = (_Float16)v[e];
    }
    acc[0] = (f32x4){0.f, 0.f, 0.f, 0.f};
    acc[1] = (f32x4){0.f, 0.f, 0.f, 0.f};
#pragma unroll
    for (int kt = 0; kt < 16; ++kt) {
      half8 ah = *(const half8*)&hpeer[lm][kt * 32 + lkb];
      acc[0] = __builtin_amdgcn_mfma_f32_16x16x32_f16(ah, wv[kt][0], acc[0], 0, 0, 0);
      acc[1] = __builtin_amdgcn_mfma_f32_16x16x32_f16(ah, wv[kt][1], acc[1], 0, 0, 0);
    }
#pragma unroll
    for (int q = 0; q < 2; ++q) {
      acc[0] = __builtin_amdgcn_mfma_f32_16x16x32_f16(ax[q], wv[16 + q][0], acc[0], 0, 0, 0);
      acc[1] = __builtin_amdgcn_mfma_f32_16x16x32_f16(ax[q], wv[16 + q][1], acc[1], 0, 0, 0);
    }
    if (t + 1 < NT) {
#pragma unroll
      for (int xt = 0; xt < 2; ++xt) {
        xr[2 * xt]     = *(const f32x4*)(xrow + (size_t)(t + 1) * ND + xt * 32);
        xr[2 * xt + 1] = *(const f32x4*)(xrow + (size_t)(t + 1) * ND + xt * 32 + 4);
      }
    }
    __syncthreads();

    float po[4] = {0.f, 0.f, 0.f, 0.f};
#pragma unroll
    for (int nt = 0; nt < 2; ++nt) {
#pragma unroll
      for (int r = 0; r < 4; ++r) {
        float hv  = tanh_fast(acc[nt][r] + bv[nt]);
        const int m = lg * 4 + r;
        const int c = nt * 16 + lm;
        const unsigned short h16 = f16b(hv);
        hpeer[m][n0 + c] = h16;
        tstage[w][c * 16 + m] = h16;
        po[r] += hv * wov[nt];
      }
    }
#pragma unroll
    for (int s = 1; s < 16; s <<= 1)
#pragma unroll
      for (int r = 0; r < 4; ++r) po[r] += __shfl_xor(po[r], s, 64);
    if (lm == 0) {
#pragma unroll
      for (int r = 0; r < 4; ++r) posum[t & 1][w][lg * 4 + r] = po[r];
    }

    {
      const ull tagbits = (ull)(unsigned short)(t + 1) << 48;
      const size_t pubb = (size_t)(t & 1) * STRBUF + mypub;
#pragma unroll
      for (int k = 0; k < 3; ++k) {
        const int g2 = lane + k * 64;
        if (g2 < GRW) {
          ull pk = tagbits;
          const int g3 = 3 * g2;
#pragma unroll
          for (int j = 0; j < 3; ++j) {
            const int p = g3 + j;
            if (p < 512) pk |= (ull)tstage[w][p] << (16 * j);
          }
          __hip_atomic_store(hglob + pubb + g2, pk,
                             __ATOMIC_RELAXED, __HIP_MEMORY_SCOPE_AGENT);
        }
      }
    }
    if (t + 1 < NT) {
      const size_t bufb = (size_t)(t & 1) * STRBUF;
#pragma unroll
      for (int k = 0; k < 9; ++k)
        if (fvalid >> k & 1u)
          fq[k] = __hip_atomic_load(hglob + bufb + foff[k],
                                    __ATOMIC_RELAXED, __HIP_MEMORY_SCOPE_AGENT);
    }
  }

  __syncthreads();
  if (w == 0 && lane < 16) {
    float s4 = posum[(NT - 1) & 1][0][lane] + posum[(NT - 1) & 1][1][lane]
             + posum[(NT - 1) & 1][2][lane] + posum[(NT - 1) & 1][3][lane];
    partial[((size_t)cb * NB + bm + lane) * NT + (NT - 1)] = s4;
  }
}

// ======================= host =======================

extern "C" void kernel_launch(void* const* d_in, const int* in_sizes, int n_in,
                              void* d_out, int out_size, void* d_ws, size_t ws_size,
                              hipStream_t stream) {
  const float* x   = (const float*)d_in[0];
  const float* wih = (const float*)d_in[1];
  const float* whh = (const float*)d_in[2];
  const float* bih = (const float*)d_in[3];
  const float* bhh = (const float*)d_in[4];
  const float* who = (const float*)d_in[5];
  const float* bho = (const float*)d_in[6];
  float* out = (float*)d_out;

  _Float16* wpk = (_Float16*)d_ws;                 // 576 KB
  const size_t wpk_halves = (size_t)18 * 4 * 8 * 64 * 8;   // 294912
  const size_t xpf_halves = (size_t)16 * NT * 8 * 64 * 16; // 128 MB
  const size_t par8_floats = (size_t)8 * NB * NT;          // 4 MB
  const size_t need_main = (wpk_halves + xpf_halves) * 2 + par8_floats * 4 + 1024;

  prep_kernel<<<144, 256, 0, stream>>>(whh, wih, wpk);

  if (ws_size >= need_main) {
    // -------- main: zero-exchange per-CU recurrence (swapped frags) --------
    _Float16* xpf = wpk + wpk_halves;
    float* partial = (float*)(xpf + xpf_halves);
    xp_kernel<<<512, 512, 0, stream>>>(x, wpk, bih, bhh, xpf);
    rnn_local<<<16, 512, 0, stream>>>(wpk, xpf, who, partial);
    combine8_kernel<<<512, 256, 0, stream>>>(partial, bho, out);
  } else {
    // -------- fallback: R16 tagged-granule pipeline (proven) --------
    ull* hglob = (ull*)(wpk + wpk_halves);
    float* partial = (float*)(hglob + (size_t)NGTOT);
    init_kernel<<<(NGTOT + 255) / 256, 256, 0, stream>>>(hglob);
    rnn_tag<<<64, 256, 0, stream>>>(x, wpk, bih, bhh, who, hglob, partial);
    combine_kernel<<<512, 256, 0, stream>>>(partial, bho, out);
  }
}